// Round 2
// baseline (818.483 us; speedup 1.0000x reference)
//
#include <hip/hip_runtime.h>
#include <math.h>

#define EPS 1e-8

constexpr int W = 32;            // time-steps per tile
constexpr int W4 = W / 4;        // float4 per LDS row
constexpr int NTHR = 512;        // threads per block
constexpr int PARTS = NTHR / W;  // 16 channel-partitions in the reduce
constexpr int CMAX = 512;        // LDS sized for C <= 512

// ---- device-scope atomic helpers (cross-XCD coherent) ----
__device__ inline unsigned long long ld_acq(const unsigned long long* p) {
  return __hip_atomic_load(p, __ATOMIC_ACQUIRE, __HIP_MEMORY_SCOPE_AGENT);
}
__device__ inline unsigned long long ld_rlx(const unsigned long long* p) {
  return __hip_atomic_load(p, __ATOMIC_RELAXED, __HIP_MEMORY_SCOPE_AGENT);
}
__device__ inline void st_rlx(unsigned long long* p, unsigned long long v) {
  __hip_atomic_store(p, v, __ATOMIC_RELAXED, __HIP_MEMORY_SCOPE_AGENT);
}
__device__ inline void st_rel(unsigned long long* p, unsigned long long v) {
  __hip_atomic_store(p, v, __ATOMIC_RELEASE, __HIP_MEMORY_SCOPE_AGENT);
}
__device__ inline double u2d(unsigned long long u) {
  return __builtin_bit_cast(double, u);
}
__device__ inline unsigned long long d2u(double d) {
  return __builtin_bit_cast(unsigned long long, d);
}

// Single-pass cumulative layernorm: stage x-tile in LDS, reduce, decoupled
// lookback for the running (sum, sumsq) prefix, apply out of LDS.
// Slot layout (8 ull each): [0]=status(0/1/2) [1,2]=aggregate [3,4]=inclusive
__global__ __launch_bounds__(NTHR, 4) void clnorm_fused(
    const float4* __restrict__ x4, const float* __restrict__ wgt,
    const float* __restrict__ bias, float4* __restrict__ y4,
    unsigned long long* __restrict__ ws_u64, int B, int C, int T, int nCh) {
  const int T4 = T >> 2;
  const int tid = threadIdx.x;

  __shared__ float x_sh[CMAX * W];     // 64 KB
  __shared__ float ps_sh[PARTS * W];   // 2 KB
  __shared__ float pq_sh[PARTS * W];   // 2 KB
  __shared__ float w_sh[CMAX];         // 2 KB
  __shared__ float b_sh[CMAX];         // 2 KB
  __shared__ __align__(16) float m_sh[W];
  __shared__ __align__(16) float r_sh[W];
  __shared__ int sh_tile;

  unsigned long long* counter = ws_u64;    // byte 0
  unsigned long long* slots = ws_u64 + 8;  // slots start at byte 64

  // Tile id from a global counter: a tile only waits on lower tile ids,
  // which were taken by blocks that started earlier -> lookback can't deadlock
  // regardless of HW dispatch order.
  if (tid == 0)
    sh_tile = (int)__hip_atomic_fetch_add(counter, 1ull, __ATOMIC_RELAXED,
                                          __HIP_MEMORY_SCOPE_AGENT);
  __syncthreads();
  const int tile = sh_tile;
  const int b = tile / nCh;
  const int chunk = tile - b * nCh;
  const int t0 = chunk * W;
  const int t40 = t0 >> 2;

  // ---- stage x[b, :, t0:t0+W] into LDS (float4; 128 B segments per c) ----
  const int nF4 = C * W4;
#pragma unroll 4
  for (int f = tid; f < nF4; f += NTHR) {
    int c = f >> 3;           // / W4
    int t4 = f & (W4 - 1);
    float4 v = make_float4(0.f, 0.f, 0.f, 0.f);
    if (t40 + t4 < T4) v = x4[(size_t)(b * C + c) * T4 + t40 + t4];
    *(float4*)&x_sh[c * W + t4 * 4] = v;
  }
  for (int c = tid; c < C; c += NTHR) {
    w_sh[c] = wgt[c];
    b_sh[c] = bias[c];
  }
  __syncthreads();

  // ---- partial column sums: thread = (part, t), 2-way LDS aliasing (free) --
  {
    int t = tid & (W - 1);
    int part = tid >> 5;
    int cPer = C / PARTS;
    int c0 = part * cPer;
    float s = 0.f, q = 0.f;
#pragma unroll 8
    for (int k = 0; k < cPer; ++k) {
      float v = x_sh[(c0 + k) * W + t];
      s += v;
      q = fmaf(v, v, q);
    }
    ps_sh[part * W + t] = s;
    pq_sh[part * W + t] = q;
  }
  __syncthreads();

  // ---- wave 0: column totals (double), in-wave scan, publish, lookback ----
  if (tid < 64) {
    const int lane = tid;
    double p_s = 0.0, p_q = 0.0;
    if (lane < W) {
#pragma unroll
      for (int p = 0; p < PARTS; ++p) {
        p_s += (double)ps_sh[p * W + lane];
        p_q += (double)pq_sh[p * W + lane];
      }
    }
    // inclusive scan across the W=32 t-columns (wave shuffle, no barriers)
    for (int off = 1; off < W; off <<= 1) {
      double vs = __shfl_up(p_s, off, 64);
      double vq = __shfl_up(p_q, off, 64);
      if (lane >= off && lane < W) {
        p_s += vs;
        p_q += vq;
      }
    }
    double A_s = __shfl(p_s, W - 1, 64);  // tile aggregate
    double A_q = __shfl(p_q, W - 1, 64);

    unsigned long long* mySlot = slots + (size_t)tile * 8;
    if (chunk == 0) {
      if (lane == 0) {  // chunk 0's inclusive == aggregate
        st_rlx(mySlot + 3, d2u(A_s));
        st_rlx(mySlot + 4, d2u(A_q));
        st_rel(mySlot + 0, 2ull);
      }
    } else if (lane == 0) {  // publish aggregate ASAP
      st_rlx(mySlot + 1, d2u(A_s));
      st_rlx(mySlot + 2, d2u(A_q));
      st_rel(mySlot + 0, 1ull);
    }

    double E_s = 0.0, E_q = 0.0;  // exclusive prefix over chunks [0, chunk)
    if (chunk > 0) {
      unsigned long long* chain = slots + (size_t)b * nCh * 8;
      int pos = chunk;
      while (true) {
        int idx = pos - 1 - lane;  // lane 0 = nearest predecessor
        const unsigned long long* ps = chain + (size_t)(idx < 0 ? 0 : idx) * 8;
        unsigned long long st = 0;
        if (idx >= 0) st = ld_acq(ps);
        unsigned long long b2 = __ballot(st == 2ull);
        unsigned long long b0 = __ballot(st == 0ull);
        bool got = false;
        bool full = false;
        double vs = 0.0, vq = 0.0;
        if (b2 != 0) {
          int l2 = __ffsll(b2) - 1;  // nearest tile with inclusive ready
          if ((b0 & ((1ull << l2) - 1ull)) == 0) {
            if (lane < l2) {
              vs = u2d(ld_rlx(ps + 1));
              vq = u2d(ld_rlx(ps + 2));
            } else if (lane == l2) {
              vs = u2d(ld_rlx(ps + 3));
              vq = u2d(ld_rlx(ps + 4));
            }
            got = true;
          }
        } else if (b0 == 0) {  // 64 aggregates ready: consume, keep walking
          vs = u2d(ld_rlx(ps + 1));
          vq = u2d(ld_rlx(ps + 2));
          full = true;
        }
        if (got || full) {
          for (int o = 32; o > 0; o >>= 1) {
            vs += __shfl_down(vs, o, 64);
            vq += __shfl_down(vq, o, 64);
          }
          vs = __shfl(vs, 0, 64);
          vq = __shfl(vq, 0, 64);
          E_s += vs;
          E_q += vq;
          if (got) break;
          pos -= 64;
        } else {
          __builtin_amdgcn_s_sleep(2);
        }
      }
      if (lane == 0) {  // publish inclusive
        st_rlx(mySlot + 3, d2u(E_s + A_s));
        st_rlx(mySlot + 4, d2u(E_q + A_q));
        st_rel(mySlot + 0, 2ull);
      }
    }

    if (lane < W) {
      int tg = t0 + lane;
      double cnt = (double)(tg + 1) * (double)C;
      double m = (E_s + p_s) / cnt;
      double var = (E_q + p_q) / cnt - m * m;
      if (var < 0.0) var = 0.0;
      m_sh[lane] = (float)m;
      r_sh[lane] = (float)(1.0 / sqrt(var + EPS));
    }
  }
  __syncthreads();

  // ---- apply out of LDS: y = (x - m[t]) * r[t] * w[c] + b[c] ----
#pragma unroll 4
  for (int f = tid; f < nF4; f += NTHR) {
    int c = f >> 3;
    int t4 = f & (W4 - 1);
    if (t40 + t4 >= T4) continue;
    float4 xv = *(const float4*)&x_sh[c * W + t4 * 4];
    float4 mv = *(const float4*)&m_sh[t4 * 4];
    float4 rv = *(const float4*)&r_sh[t4 * 4];
    float wc = w_sh[c], bc = b_sh[c];
    float4 yv;
    yv.x = (xv.x - mv.x) * rv.x * wc + bc;
    yv.y = (xv.y - mv.y) * rv.y * wc + bc;
    yv.z = (xv.z - mv.z) * rv.z * wc + bc;
    yv.w = (xv.w - mv.w) * rv.w * wc + bc;
    y4[(size_t)(b * C + c) * T4 + t40 + t4] = yv;
  }
}

extern "C" void kernel_launch(void* const* d_in, const int* in_sizes, int n_in,
                              void* d_out, int out_size, void* d_ws,
                              size_t ws_size, hipStream_t stream) {
  const float* x = (const float*)d_in[0];
  const float* w = (const float*)d_in[1];
  const float* bias = (const float*)d_in[2];
  float* out = (float*)d_out;

  const int B = 4;                // from reference setup_inputs
  int C = in_sizes[1];            // 512
  int T = in_sizes[0] / (B * C);  // 32000
  int nCh = (T + W - 1) / W;      // 1000
  int nTiles = B * nCh;           // 4000

  // Zero the counter + status slots (graph-capture-safe async memset).
  size_t ctrlBytes = 64 + (size_t)nTiles * 64;
  hipMemsetAsync(d_ws, 0, ctrlBytes, stream);

  clnorm_fused<<<dim3(nTiles), NTHR, 0, stream>>>(
      (const float4*)x, w, bias, (float4*)out, (unsigned long long*)d_ws, B, C,
      T, nCh);
}

// Round 4
// 514.400 us; speedup vs baseline: 1.5911x; 1.5911x over previous
//
#include <hip/hip_runtime.h>
#include <math.h>

#define EPS 1e-8

constexpr int W = 32;      // time-steps per chunk
constexpr int W4 = W / 4;  // float4 columns per chunk (8)
constexpr int NTHR = 512;  // 8 waves per block
constexpr int CMAX = 512;  // this problem: C == 512 (hardcoded mapping below)

struct __align__(16) dbl2 {
  double s, q;
};

// ---------------- K1: chunk reduce + within-chunk prefix ----------------
// One block per (ch, b). Thread (p, t4): p = tid>>3 owns 8 contiguous
// channels, t4 = tid&7 one float4 column. Reads x once (float4, 16 B/lane);
// writes scanBuf[b*T + t] = within-chunk inclusive column prefix (double)
// and aggBuf[b*nCh + ch] = chunk totals (double).
__global__ __launch_bounds__(NTHR, 4) void clnorm_reduce(
    const float4* __restrict__ x4, dbl2* __restrict__ scanBuf,
    dbl2* __restrict__ aggBuf, int B, int C, int T, int nCh) {
  const int T4 = T >> 2;
  const int ch = blockIdx.x;
  const int b = blockIdx.y;
  const int tid = threadIdx.x;
  const int t0 = ch * W;
  const int t40 = t0 >> 2;

  const int p = tid >> 3;         // 64 channel groups
  const int t4 = tid & (W4 - 1);  // 8 float4 columns
  const int cPer = C / 64;        // 8 channels per group (C = 512)

  float4 s4 = make_float4(0.f, 0.f, 0.f, 0.f);
  float4 q4 = make_float4(0.f, 0.f, 0.f, 0.f);
  if (t40 + t4 < T4) {
    const float4* xp = x4 + ((size_t)b * C + (size_t)p * cPer) * T4 + t40 + t4;
#pragma unroll
    for (int k = 0; k < cPer; ++k) {
      float4 v = xp[(size_t)k * T4];  // 8x128B segments per wave instr
      s4.x += v.x;
      s4.y += v.y;
      s4.z += v.z;
      s4.w += v.w;
      q4.x = fmaf(v.x, v.x, q4.x);
      q4.y = fmaf(v.y, v.y, q4.y);
      q4.z = fmaf(v.z, v.z, q4.z);
      q4.w = fmaf(v.w, v.w, q4.w);
    }
  }
  __shared__ float4 ps_sh[64 * W4];  // 4 KB; float view: [p*32 + t]
  __shared__ float4 pq_sh[64 * W4];  // 4 KB
  ps_sh[p * W4 + t4] = s4;
  pq_sh[p * W4 + t4] = q4;
  __syncthreads();

  if (tid < 64) {
    const int lane = tid;
    double as = 0.0, aq = 0.0;
    if (lane < W) {
      const float* psf = (const float*)ps_sh;
      const float* pqf = (const float*)pq_sh;
#pragma unroll 8
      for (int pp = 0; pp < 64; ++pp) {
        // lanes 0..31 read consecutive floats -> conflict-free
        as += (double)psf[pp * W + lane];
        aq += (double)pqf[pp * W + lane];
      }
    }
    // inclusive scan across the W=32 t-columns (wave shuffle)
    for (int off = 1; off < W; off <<= 1) {
      double vs = __shfl_up(as, off, 64);
      double vq = __shfl_up(aq, off, 64);
      if (lane >= off && lane < W) {
        as += vs;
        aq += vq;
      }
    }
    if (lane < W && t0 + lane < T)
      scanBuf[(size_t)b * T + t0 + lane] = dbl2{as, aq};
    if (lane == W - 1) aggBuf[(size_t)b * nCh + ch] = dbl2{as, aq};
  }
}

// ---------------- K2: redundant-parallel offset + apply ----------------
// One block per (ch, b). Wave 0 sums this batch's predecessor chunk
// aggregates itself (<=16 KB from L2, no waiting), merges with scanBuf,
// computes mean/rstd; all threads then apply. x-loads are issued FIRST so
// their (mostly L3-hit) latency hides under the offset computation.
__global__ __launch_bounds__(NTHR, 4) void clnorm_apply(
    const float4* __restrict__ x4, const float* __restrict__ wgt,
    const float* __restrict__ bias, const dbl2* __restrict__ scanBuf,
    const dbl2* __restrict__ aggBuf, float4* __restrict__ y4, int B, int C,
    int T, int nCh) {
  const int T4 = T >> 2;
  const int ch = blockIdx.x;
  const int b = blockIdx.y;
  const int tid = threadIdx.x;
  const int t0 = ch * W;
  const int t40 = t0 >> 2;

  __shared__ float w_sh[CMAX];
  __shared__ float b_sh[CMAX];
  __shared__ __align__(16) float m_sh[W];
  __shared__ __align__(16) float r_sh[W];

  // thread (c0, t4): c0 = tid>>3 base channel, strided by 64; t4 = tid&7
  const int c0 = tid >> 3;
  const int t4 = tid & (W4 - 1);
  const bool inb = (t40 + t4 < T4);

  // issue the 8 x float4 loads early (C == 512: channels c0 + j*64)
  float4 xv[8];
  const float4* xp = x4 + ((size_t)b * C + c0) * T4 + t40 + t4;
  if (inb) {
#pragma unroll
    for (int j = 0; j < 8; ++j) xv[j] = xp[(size_t)(j * 64) * T4];
  }
  for (int c = tid; c < C; c += NTHR) {
    w_sh[c] = wgt[c];
    b_sh[c] = bias[c];
  }

  if (tid < 64) {
    const int lane = tid;
    // exclusive chunk offset over chunks [0, ch) of this batch
    double es = 0.0, eq = 0.0;
    const dbl2* ag = aggBuf + (size_t)b * nCh;
    for (int base = 0; base < ch; base += 64) {
      int i = base + lane;
      if (i < ch) {
        dbl2 a = ag[i];
        es += a.s;
        eq += a.q;
      }
    }
#pragma unroll
    for (int o = 32; o > 0; o >>= 1) {
      es += __shfl_xor(es, o, 64);
      eq += __shfl_xor(eq, o, 64);
    }
    if (lane < W && t0 + lane < T) {
      dbl2 pp = scanBuf[(size_t)b * T + t0 + lane];
      double cnt = (double)(t0 + lane + 1) * (double)C;
      double m = (es + pp.s) / cnt;
      double var = (eq + pp.q) / cnt - m * m;
      if (var < 0.0) var = 0.0;
      m_sh[lane] = (float)m;
      r_sh[lane] = (float)(1.0 / sqrt(var + EPS));
    }
  }
  __syncthreads();

  if (inb) {
    float4 mv = *(const float4*)&m_sh[t4 * 4];
    float4 rv = *(const float4*)&r_sh[t4 * 4];
    float4* yp = y4 + ((size_t)b * C + c0) * T4 + t40 + t4;
#pragma unroll
    for (int j = 0; j < 8; ++j) {
      int c = c0 + j * 64;
      float wc = w_sh[c], bc = b_sh[c];
      float4 yv;
      yv.x = (xv[j].x - mv.x) * rv.x * wc + bc;
      yv.y = (xv[j].y - mv.y) * rv.y * wc + bc;
      yv.z = (xv[j].z - mv.z) * rv.z * wc + bc;
      yv.w = (xv[j].w - mv.w) * rv.w * wc + bc;
      yp[(size_t)(j * 64) * T4] = yv;
    }
  }
}

extern "C" void kernel_launch(void* const* d_in, const int* in_sizes, int n_in,
                              void* d_out, int out_size, void* d_ws,
                              size_t ws_size, hipStream_t stream) {
  const float4* x4 = (const float4*)d_in[0];
  const float* w = (const float*)d_in[1];
  const float* bias = (const float*)d_in[2];
  float4* y4 = (float4*)d_out;

  int B = 4;                      // from reference setup_inputs
  int C = in_sizes[1];            // 512
  int T = in_sizes[0] / (B * C);  // 32000
  int nCh = (T + W - 1) / W;      // 1000

  // Workspace: scanBuf [B*T] dbl2 (2 MB) | aggBuf [B*nCh] dbl2 (64 KB).
  // Both fully written by K1 before K2 reads -> no init/memset needed.
  dbl2* scanBuf = (dbl2*)d_ws;
  dbl2* aggBuf = scanBuf + (size_t)B * T;

  dim3 g(nCh, B);
  clnorm_reduce<<<g, NTHR, 0, stream>>>(x4, scanBuf, aggBuf, B, C, T, nCh);
  clnorm_apply<<<g, NTHR, 0, stream>>>(x4, w, bias, scanBuf, aggBuf, y4, B, C,
                                       T, nCh);
}

// Round 5
// 512.800 us; speedup vs baseline: 1.5961x; 1.0031x over previous
//
#include <hip/hip_runtime.h>
#include <math.h>

#define EPS 1e-8

constexpr int W = 32;      // time-steps per chunk
constexpr int W4 = W / 4;  // float4 columns per chunk (8)
constexpr int NTHR = 256;  // 4 waves per block
constexpr int CMAX = 512;  // this problem: C == 512 (mapping hardcoded below)

// ---------------- K1: chunk reduce + within-chunk prefix ----------------
// One block per (ch, b). Thread (p, t4): p = tid>>3 owns 16 contiguous
// channels, t4 = tid&7 one float4 column (16 B/lane reads).
// Tail split: wave 0 reduces/scans sums, wave 1 sumsq (SoA outputs).
__global__ __launch_bounds__(NTHR, 4) void clnorm_reduce(
    const float4* __restrict__ x4, double* __restrict__ scanS,
    double* __restrict__ scanQ, double* __restrict__ aggS,
    double* __restrict__ aggQ, int B, int C, int T, int nCh) {
  const int T4 = T >> 2;
  const int ch = blockIdx.x;
  const int b = blockIdx.y;
  const int tid = threadIdx.x;
  const int t0 = ch * W;
  const int t40 = t0 >> 2;

  const int p = tid >> 3;         // 32 channel groups
  const int t4 = tid & (W4 - 1);  // 8 float4 columns
  const int cPer = C / 32;        // 16 channels per group (C = 512)

  float4 s4 = make_float4(0.f, 0.f, 0.f, 0.f);
  float4 q4 = make_float4(0.f, 0.f, 0.f, 0.f);
  if (t40 + t4 < T4) {
    const float4* xp = x4 + ((size_t)b * C + (size_t)p * cPer) * T4 + t40 + t4;
#pragma unroll 4
    for (int k = 0; k < cPer; ++k) {
      float4 v = xp[(size_t)k * T4];  // 128 B row segments (full cache lines)
      s4.x += v.x;
      s4.y += v.y;
      s4.z += v.z;
      s4.w += v.w;
      q4.x = fmaf(v.x, v.x, q4.x);
      q4.y = fmaf(v.y, v.y, q4.y);
      q4.z = fmaf(v.z, v.z, q4.z);
      q4.w = fmaf(v.w, v.w, q4.w);
    }
  }
  __shared__ float4 ps4[32 * W4];  // 4 KB; float view [p][t] = [32][32]
  __shared__ float4 pq4[32 * W4];  // 4 KB
  ps4[p * W4 + t4] = s4;
  pq4[p * W4 + t4] = q4;
  __syncthreads();

  const int wave = tid >> 6;
  const int lane = tid & 63;
  if (wave < 2 && lane < W) {
    const float* src = (wave == 0) ? (const float*)ps4 : (const float*)pq4;
    double a = 0.0;
#pragma unroll 8
    for (int pp = 0; pp < 32; ++pp)
      a += (double)src[pp * W + lane];  // lanes 0..31 consecutive: no conflict
    // inclusive scan across the W=32 t-columns (wave shuffle)
    for (int off = 1; off < W; off <<= 1) {
      double v = __shfl_up(a, off, 64);
      if (lane >= off) a += v;
    }
    if (t0 + lane < T) {
      double* dst = (wave == 0) ? scanS : scanQ;
      dst[(size_t)b * T + t0 + lane] = a;
    }
    if (lane == W - 1) {
      double* ad = (wave == 0) ? aggS : aggQ;
      ad[(size_t)b * nCh + ch] = a;
    }
  }
}

// ---------------- K1.5: exclusive scan of chunk aggregates ----------------
// One block per batch; handles nCh <= 1024 (here nCh = 1000).
__global__ __launch_bounds__(512) void clnorm_scanagg(
    const double* __restrict__ aggS, const double* __restrict__ aggQ,
    double* __restrict__ offS, double* __restrict__ offQ, int nCh) {
  const int b = blockIdx.x;
  const int tid = threadIdx.x;
  __shared__ double shS[512];
  __shared__ double shQ[512];

  const int i0 = tid * 2, i1 = tid * 2 + 1;
  const size_t base = (size_t)b * nCh;
  double s0 = (i0 < nCh) ? aggS[base + i0] : 0.0;
  double s1 = (i1 < nCh) ? aggS[base + i1] : 0.0;
  double q0 = (i0 < nCh) ? aggQ[base + i0] : 0.0;
  double q1 = (i1 < nCh) ? aggQ[base + i1] : 0.0;
  shS[tid] = s0 + s1;
  shQ[tid] = q0 + q1;
  __syncthreads();
  for (int off = 1; off < 512; off <<= 1) {  // Hillis-Steele inclusive
    double vs = (tid >= off) ? shS[tid - off] : 0.0;
    double vq = (tid >= off) ? shQ[tid - off] : 0.0;
    __syncthreads();
    shS[tid] += vs;
    shQ[tid] += vq;
    __syncthreads();
  }
  double exS = shS[tid] - (s0 + s1);  // exclusive across threads
  double exQ = shQ[tid] - (q0 + q1);
  if (i0 < nCh) {
    offS[base + i0] = exS;
    offQ[base + i0] = exQ;
  }
  if (i1 < nCh) {
    offS[base + i1] = exS + s0;
    offQ[base + i1] = exQ + q0;
  }
}

// ---------------- K2: mean/rstd + apply (streaming) ----------------
// One block per (ch, b). Tail = 32 lanes x {2 scalar loads + ~10 F64 ops}.
__global__ __launch_bounds__(NTHR, 4) void clnorm_apply(
    const float4* __restrict__ x4, const float* __restrict__ wgt,
    const float* __restrict__ bias, const double* __restrict__ scanS,
    const double* __restrict__ scanQ, const double* __restrict__ offS,
    const double* __restrict__ offQ, float4* __restrict__ y4, int B, int C,
    int T, int nCh) {
  const int T4 = T >> 2;
  const int ch = blockIdx.x;
  const int b = blockIdx.y;
  const int tid = threadIdx.x;
  const int t0 = ch * W;
  const int t40 = t0 >> 2;

  __shared__ float w_sh[CMAX];
  __shared__ float b_sh[CMAX];
  __shared__ __align__(16) float m_sh[W];
  __shared__ __align__(16) float r_sh[W];

  for (int c = tid; c < C; c += NTHR) {
    w_sh[c] = wgt[c];
    b_sh[c] = bias[c];
  }

  if (tid < W && t0 + tid < T) {
    double s = offS[(size_t)b * nCh + ch] + scanS[(size_t)b * T + t0 + tid];
    double q = offQ[(size_t)b * nCh + ch] + scanQ[(size_t)b * T + t0 + tid];
    double cnt = (double)(t0 + tid + 1) * (double)C;
    double m = s / cnt;
    double var = q / cnt - m * m;
    if (var < 0.0) var = 0.0;
    m_sh[tid] = (float)m;
    r_sh[tid] = (float)(1.0 / sqrt(var + EPS));
  }
  __syncthreads();

  // thread (c0, t4): c0 = tid>>3 base channel (strided by 32), t4 = tid&7
  const int c0 = tid >> 3;
  const int t4 = tid & (W4 - 1);
  if (t40 + t4 >= T4) return;
  const float4 mv = *(const float4*)&m_sh[t4 * 4];
  const float4 rv = *(const float4*)&r_sh[t4 * 4];
  const float4* xp = x4 + ((size_t)b * C + c0) * T4 + t40 + t4;
  float4* yp = y4 + ((size_t)b * C + c0) * T4 + t40 + t4;
#pragma unroll 4
  for (int j = 0; j < CMAX / 32; ++j) {  // 16 iterations over channels
    int c = c0 + j * 32;
    float4 xv = xp[(size_t)(j * 32) * T4];
    float wc = w_sh[c], bc = b_sh[c];
    float4 yv;
    yv.x = (xv.x - mv.x) * rv.x * wc + bc;
    yv.y = (xv.y - mv.y) * rv.y * wc + bc;
    yv.z = (xv.z - mv.z) * rv.z * wc + bc;
    yv.w = (xv.w - mv.w) * rv.w * wc + bc;
    yp[(size_t)(j * 32) * T4] = yv;
  }
}

extern "C" void kernel_launch(void* const* d_in, const int* in_sizes, int n_in,
                              void* d_out, int out_size, void* d_ws,
                              size_t ws_size, hipStream_t stream) {
  const float4* x4 = (const float4*)d_in[0];
  const float* w = (const float*)d_in[1];
  const float* bias = (const float*)d_in[2];
  float4* y4 = (float4*)d_out;

  int B = 4;                      // from reference setup_inputs
  int C = in_sizes[1];            // 512
  int T = in_sizes[0] / (B * C);  // 32000
  int nCh = (T + W - 1) / W;      // 1000

  // Workspace (doubles): scanS[B*T] | scanQ[B*T] | aggS | aggQ | offS | offQ
  double* scanS = (double*)d_ws;
  double* scanQ = scanS + (size_t)B * T;
  double* aggS = scanQ + (size_t)B * T;
  double* aggQ = aggS + (size_t)B * nCh;
  double* offS = aggQ + (size_t)B * nCh;
  double* offQ = offS + (size_t)B * nCh;

  dim3 g(nCh, B);
  clnorm_reduce<<<g, NTHR, 0, stream>>>(x4, scanS, scanQ, aggS, aggQ, B, C, T,
                                        nCh);
  clnorm_scanagg<<<dim3(B), 512, 0, stream>>>(aggS, aggQ, offS, offQ, nCh);
  clnorm_apply<<<g, NTHR, 0, stream>>>(x4, w, bias, scanS, scanQ, offS, offQ,
                                       y4, B, C, T, nCh);
}

// Round 7
// 470.911 us; speedup vs baseline: 1.7381x; 1.0890x over previous
//
#include <hip/hip_runtime.h>
#include <math.h>

#define EPS 1e-8

constexpr int W = 128;     // time-steps per chunk (512 B per channel row)
constexpr int W4 = W / 4;  // 32 float4 columns per chunk
constexpr int NTHR = 256;  // 4 waves
constexpr int RG = 8;      // row groups: tid>>5, each owns C/RG channels
constexpr int CMAX = 512;  // this problem: C == 512

typedef float vf4 __attribute__((ext_vector_type(4)));  // native vector for NT

// ---------------- K1: chunk reduce + within-chunk prefix ----------------
// Thread (rg, t4): rg = tid>>5 owns rows {rg, rg+8, ...} (64 rows),
// t4 = tid&31 one float4 column. Wave instr = 2 x 512 B contiguous segments.
__global__ __launch_bounds__(NTHR, 4) void clnorm_reduce(
    const float4* __restrict__ x4, double* __restrict__ scanS,
    double* __restrict__ scanQ, double* __restrict__ aggS,
    double* __restrict__ aggQ, int B, int C, int T, int nCh) {
  const int T4 = T >> 2;
  const int ch = blockIdx.x;
  const int b = blockIdx.y;
  const int tid = threadIdx.x;
  const int t0 = ch * W;
  const int t40 = t0 >> 2;

  const int rg = tid >> 5;        // 8 row groups
  const int t4 = tid & (W4 - 1);  // 32 float4 columns
  const int rowsPer = C / RG;     // 64 (C = 512)

  float4 s4 = make_float4(0.f, 0.f, 0.f, 0.f);
  float4 q4 = make_float4(0.f, 0.f, 0.f, 0.f);
  if (t40 + t4 < T4) {
    const float4* xp = x4 + ((size_t)b * C + rg) * T4 + t40 + t4;
#pragma unroll 8
    for (int k = 0; k < rowsPer; ++k) {
      float4 v = xp[(size_t)k * RG * T4];
      s4.x += v.x;
      s4.y += v.y;
      s4.z += v.z;
      s4.w += v.w;
      q4.x = fmaf(v.x, v.x, q4.x);
      q4.y = fmaf(v.y, v.y, q4.y);
      q4.z = fmaf(v.z, v.z, q4.z);
      q4.w = fmaf(v.w, v.w, q4.w);
    }
  }
  __shared__ float4 ps4[RG * W4];  // 4 KB; float view [rg][t] = [8][128]
  __shared__ float4 pq4[RG * W4];  // 4 KB
  ps4[rg * W4 + t4] = s4;
  pq4[rg * W4 + t4] = q4;
  __syncthreads();

  // Tail: wave 0 scans sums, wave 1 scans sumsq. Lane owns 2 t-columns.
  const int wave = tid >> 6;
  const int lane = tid & 63;
  if (wave < 2) {
    const float* src = (wave == 0) ? (const float*)ps4 : (const float*)pq4;
    const int ta = lane * 2;
    double a0 = 0.0, a1 = 0.0;
#pragma unroll
    for (int p = 0; p < RG; ++p) {
      a0 += (double)src[p * W + ta];  // stride-2: 2-way conflict (free)
      a1 += (double)src[p * W + ta + 1];
    }
    const double pair = a0 + a1;
    double incl = pair;  // inclusive wave scan of pair totals
    for (int off = 1; off < 64; off <<= 1) {
      double v = __shfl_up(incl, off, 64);
      if (lane >= off) incl += v;
    }
    const double excl = incl - pair;
    double* dst = (wave == 0) ? scanS : scanQ;
    if (t0 + ta < T) {
      dst[(size_t)b * T + t0 + ta] = excl + a0;
      dst[(size_t)b * T + t0 + ta + 1] = excl + pair;
    }
    if (lane == 63) {
      double* ad = (wave == 0) ? aggS : aggQ;
      ad[(size_t)b * nCh + ch] = incl;  // chunk total
    }
  }
}

// ---------------- K1.5: exclusive scan of chunk aggregates ----------------
// One block per batch; sequential 256-wide rounds with carry (nCh = 250).
__global__ __launch_bounds__(256) void clnorm_scanagg(
    const double* __restrict__ aggS, const double* __restrict__ aggQ,
    double* __restrict__ offS, double* __restrict__ offQ, int nCh) {
  const int b = blockIdx.x;
  const int tid = threadIdx.x;
  __shared__ double shS[256];
  __shared__ double shQ[256];
  const size_t base = (size_t)b * nCh;
  double carS = 0.0, carQ = 0.0;
  for (int r0 = 0; r0 < nCh; r0 += 256) {
    const int i = r0 + tid;
    double s = (i < nCh) ? aggS[base + i] : 0.0;
    double q = (i < nCh) ? aggQ[base + i] : 0.0;
    shS[tid] = s;
    shQ[tid] = q;
    __syncthreads();
    for (int off = 1; off < 256; off <<= 1) {  // Hillis-Steele inclusive
      double vs = (tid >= off) ? shS[tid - off] : 0.0;
      double vq = (tid >= off) ? shQ[tid - off] : 0.0;
      __syncthreads();
      shS[tid] += vs;
      shQ[tid] += vq;
      __syncthreads();
    }
    if (i < nCh) {
      offS[base + i] = carS + shS[tid] - s;  // exclusive
      offQ[base + i] = carQ + shQ[tid] - q;
    }
    carS += shS[255];
    carQ += shQ[255];
    __syncthreads();
  }
}

// ---------------- K2: mean/rstd + apply (streaming) ----------------
// Reversed tile order: process what K1 streamed LAST first -> L3 hits.
// Non-temporal x loads / y stores keep L3 from being evicted by y traffic.
__global__ __launch_bounds__(NTHR, 4) void clnorm_apply(
    const float4* __restrict__ x4, const float* __restrict__ wgt,
    const float* __restrict__ bias, const double* __restrict__ scanS,
    const double* __restrict__ scanQ, const double* __restrict__ offS,
    const double* __restrict__ offQ, float4* __restrict__ y4, int B, int C,
    int T, int nCh) {
  const int T4 = T >> 2;
  const int ch = nCh - 1 - blockIdx.x;  // reversed
  const int b = B - 1 - blockIdx.y;     // reversed
  const int tid = threadIdx.x;
  const int t0 = ch * W;
  const int t40 = t0 >> 2;

  __shared__ float w_sh[CMAX];
  __shared__ float b_sh[CMAX];
  __shared__ __align__(16) float m_sh[W];
  __shared__ __align__(16) float r_sh[W];

  for (int c = tid; c < C; c += NTHR) {
    w_sh[c] = wgt[c];
    b_sh[c] = bias[c];
  }
  if (tid < W && t0 + tid < T) {
    double s = offS[(size_t)b * nCh + ch] + scanS[(size_t)b * T + t0 + tid];
    double q = offQ[(size_t)b * nCh + ch] + scanQ[(size_t)b * T + t0 + tid];
    double cnt = (double)(t0 + tid + 1) * (double)C;
    double m = s / cnt;
    double var = q / cnt - m * m;
    if (var < 0.0) var = 0.0;
    m_sh[tid] = (float)m;
    r_sh[tid] = (float)(1.0 / sqrt(var + EPS));
  }
  __syncthreads();

  const int rg = tid >> 5;
  const int t4 = tid & (W4 - 1);
  if (t40 + t4 >= T4) return;
  const float4 mv = ((const float4*)m_sh)[t4];
  const float4 rv = ((const float4*)r_sh)[t4];
  const vf4* xp =
      (const vf4*)(x4 + ((size_t)b * C + rg) * T4 + t40 + t4);
  vf4* yp = (vf4*)(y4 + ((size_t)b * C + rg) * T4 + t40 + t4);
  const int rowsPer = C / RG;  // 64
#pragma unroll 8
  for (int k = 0; k < rowsPer; ++k) {
    const int c = rg + k * RG;
    vf4 xv = __builtin_nontemporal_load(xp + (size_t)k * RG * T4);
    const float wc = w_sh[c], bc = b_sh[c];
    vf4 yv;
    yv.x = (xv.x - mv.x) * rv.x * wc + bc;
    yv.y = (xv.y - mv.y) * rv.y * wc + bc;
    yv.z = (xv.z - mv.z) * rv.z * wc + bc;
    yv.w = (xv.w - mv.w) * rv.w * wc + bc;
    __builtin_nontemporal_store(yv, yp + (size_t)k * RG * T4);
  }
}

extern "C" void kernel_launch(void* const* d_in, const int* in_sizes, int n_in,
                              void* d_out, int out_size, void* d_ws,
                              size_t ws_size, hipStream_t stream) {
  const float4* x4 = (const float4*)d_in[0];
  const float* w = (const float*)d_in[1];
  const float* bias = (const float*)d_in[2];
  float4* y4 = (float4*)d_out;

  int B = 4;                      // from reference setup_inputs
  int C = in_sizes[1];            // 512
  int T = in_sizes[0] / (B * C);  // 32000
  int nCh = (T + W - 1) / W;      // 250

  // Workspace (doubles): scanS[B*T] | scanQ[B*T] | aggS | aggQ | offS | offQ
  double* scanS = (double*)d_ws;
  double* scanQ = scanS + (size_t)B * T;
  double* aggS = scanQ + (size_t)B * T;
  double* aggQ = aggS + (size_t)B * nCh;
  double* offS = aggQ + (size_t)B * nCh;
  double* offQ = offS + (size_t)B * nCh;

  dim3 g(nCh, B);
  clnorm_reduce<<<g, NTHR, 0, stream>>>(x4, scanS, scanQ, aggS, aggQ, B, C, T,
                                        nCh);
  clnorm_scanagg<<<dim3(B), 256, 0, stream>>>(aggS, aggQ, offS, offQ, nCh);
  clnorm_apply<<<g, NTHR, 0, stream>>>(x4, w, bias, scanS, scanQ, offS, offQ,
                                       y4, B, C, T, nCh);
}